// Round 2
// baseline (575.745 us; speedup 1.0000x reference)
//
#include <hip/hip_runtime.h>
#include <math.h>

// NoisyTopkRouter: B=4 S=4096 D=2048 E=16 K=2, TEMPERATURE=1. rows = 16384.
// out layout (fp32): router_output [16384*16] | indices-as-float [16384*2] | aux_loss [1]
// Round 2: 1024 blocks x 16 rows, 4 waves x 512-d slices, per-wave double-buffered
// LDS + register prefetch, no barriers in main loop. 4 blocks/CU co-resident.

#define DDIM 2048
#define NEXP 16
#define RPB 16            // rows per block
#define WAVE_D 512
#define CHUNK 16
#define NCH 32            // WAVE_D / CHUNK
#define XSTR 18           // x LDS row stride (pad: conflict-free reads, 18*rg distinct mod 32)
#define WSTR 36           // w LDS row stride (32 cols + 4 pad)
#define WREG 1728         // floats per wave region: x dbuf 2*16*18=576, w dbuf 2*16*36=1152
#define IDX_OFF 262144
#define AUX_OFF 294912
#define NBLK 1024

__global__ __launch_bounds__(256, 4) void router_main_k(
    const float* __restrict__ x, const float* __restrict__ wr,
    const float* __restrict__ br, const float* __restrict__ wn,
    const float* __restrict__ bn, const float* __restrict__ eps,
    float* __restrict__ out, float* __restrict__ wsp) {
  __shared__ float smem[4 * WREG];  // 27648 B

  const int tid  = threadIdx.x;
  const int wave = tid >> 6;
  const int lane = tid & 63;
  const int rg   = lane >> 3;        // 0..7 -> rows {rg, rg+8}
  const int q4   = (lane & 7) * 4;   // col group (0..31 in steps of 4): 0..15 route, 16..31 noise
  const int row_base = blockIdx.x * RPB;

  float* reg = smem + wave * WREG;

  // staging decomposition: 64 lanes cover 16 rows x 4 float4 (one chunk)
  const int sr = lane >> 2;          // 0..15
  const int sc = (lane & 3) * 4;     // 0,4,8,12
  const float* xsrc  = x  + (size_t)(row_base + sr) * DDIM + wave * WAVE_D + sc;
  const float* wrsrc = wr + (size_t)(wave * WAVE_D + sr) * NEXP + sc;
  const float* wnsrc = wn + (size_t)(wave * WAVE_D + sr) * NEXP + sc;
  const int xs_off = sr * XSTR + sc;
  const int ws_off = sr * WSTR + sc;

  float4 acc0 = make_float4(0.f, 0.f, 0.f, 0.f);  // row rg
  float4 acc1 = make_float4(0.f, 0.f, 0.f, 0.f);  // row rg+8

  // ---- prologue: stage chunk 0 into buffer 0 ----
  float4 xg  = *(const float4*)(xsrc);
  float4 wg0 = *(const float4*)(wrsrc);
  float4 wg1 = *(const float4*)(wnsrc);
  *(float4*)(reg + xs_off)            = xg;
  *(float4*)(reg + 576 + ws_off)      = wg0;
  *(float4*)(reg + 576 + 16 + ws_off) = wg1;

  #pragma unroll 2
  for (int k = 0; k < NCH; ++k) {
    const int cur = k & 1;
    // prefetch chunk k+1 into registers (in flight during compute)
    if (k + 1 < NCH) {
      xg  = *(const float4*)(xsrc + (k + 1) * CHUNK);
      wg0 = *(const float4*)(wrsrc + (size_t)(k + 1) * CHUNK * NEXP);
      wg1 = *(const float4*)(wnsrc + (size_t)(k + 1) * CHUNK * NEXP);
    }
    const float* xbc = reg + cur * 288;
    const float* wbc = reg + 576 + cur * 576;
    #pragma unroll
    for (int dd = 0; dd < CHUNK; dd += 4) {
      float4 w0 = *(const float4*)(wbc + (dd + 0) * WSTR + q4);
      float4 w1 = *(const float4*)(wbc + (dd + 1) * WSTR + q4);
      float4 w2 = *(const float4*)(wbc + (dd + 2) * WSTR + q4);
      float4 w3 = *(const float4*)(wbc + (dd + 3) * WSTR + q4);
      float4 x0 = *(const float4*)(xbc + rg * XSTR + dd);
      float4 x1 = *(const float4*)(xbc + (rg + 8) * XSTR + dd);
      acc0.x = fmaf(x0.w, w3.x, fmaf(x0.z, w2.x, fmaf(x0.y, w1.x, fmaf(x0.x, w0.x, acc0.x))));
      acc0.y = fmaf(x0.w, w3.y, fmaf(x0.z, w2.y, fmaf(x0.y, w1.y, fmaf(x0.x, w0.y, acc0.y))));
      acc0.z = fmaf(x0.w, w3.z, fmaf(x0.z, w2.z, fmaf(x0.y, w1.z, fmaf(x0.x, w0.z, acc0.z))));
      acc0.w = fmaf(x0.w, w3.w, fmaf(x0.z, w2.w, fmaf(x0.y, w1.w, fmaf(x0.x, w0.w, acc0.w))));
      acc1.x = fmaf(x1.w, w3.x, fmaf(x1.z, w2.x, fmaf(x1.y, w1.x, fmaf(x1.x, w0.x, acc1.x))));
      acc1.y = fmaf(x1.w, w3.y, fmaf(x1.z, w2.y, fmaf(x1.y, w1.y, fmaf(x1.x, w0.y, acc1.y))));
      acc1.z = fmaf(x1.w, w3.z, fmaf(x1.z, w2.z, fmaf(x1.y, w1.z, fmaf(x1.x, w0.z, acc1.z))));
      acc1.w = fmaf(x1.w, w3.w, fmaf(x1.z, w2.w, fmaf(x1.y, w1.w, fmaf(x1.x, w0.w, acc1.w))));
    }
    // write prefetched chunk into the other buffer
    if (k + 1 < NCH) {
      const int nxt = cur ^ 1;
      *(float4*)(reg + nxt * 288 + xs_off)            = xg;
      *(float4*)(reg + 576 + nxt * 576 + ws_off)      = wg0;
      *(float4*)(reg + 576 + nxt * 576 + 16 + ws_off) = wg1;
    }
  }

  // ---- cross-wave reduction + per-row epilogue ----
  __syncthreads();                  // all waves done with their staging regions
  float* pb = reg;                  // reuse wave region: partials [16][36]
  *(float4*)(pb + rg * WSTR + q4)       = acc0;
  *(float4*)(pb + (rg + 8) * WSTR + q4) = acc1;
  __syncthreads();

  if (tid < RPB) {
    const int row_l = tid;
    const int row_g = row_base + row_l;
    float c[32];
    #pragma unroll
    for (int g = 0; g < 8; ++g) {
      float4 a0 = *(const float4*)(smem + 0 * WREG + row_l * WSTR + g * 4);
      float4 a1 = *(const float4*)(smem + 1 * WREG + row_l * WSTR + g * 4);
      float4 a2 = *(const float4*)(smem + 2 * WREG + row_l * WSTR + g * 4);
      float4 a3 = *(const float4*)(smem + 3 * WREG + row_l * WSTR + g * 4);
      c[g * 4 + 0] = (a0.x + a1.x) + (a2.x + a3.x);
      c[g * 4 + 1] = (a0.y + a1.y) + (a2.y + a3.y);
      c[g * 4 + 2] = (a0.z + a1.z) + (a2.z + a3.z);
      c[g * 4 + 3] = (a0.w + a1.w) + (a2.w + a3.w);
    }

    float brv[16], bnv[16], ev[16];
    #pragma unroll
    for (int g = 0; g < 4; ++g) {
      *(float4*)(brv + g * 4) = *(const float4*)(br + g * 4);
      *(float4*)(bnv + g * 4) = *(const float4*)(bn + g * 4);
      *(float4*)(ev  + g * 4) = *(const float4*)(eps + (size_t)row_g * NEXP + g * 4);
    }

    float s[16];
    #pragma unroll
    for (int e = 0; e < 16; ++e) {
      float lg = c[e] + brv[e];
      float nz = c[16 + e] + bnv[e];
      float sp = fmaxf(nz, 0.f) + log1pf(expf(-fabsf(nz)));  // stable softplus
      s[e] = lg + ev[e] * sp;                                 // TEMPERATURE == 1
    }

    // top-2 (ties -> lowest index, matching lax.top_k)
    float b1 = s[0]; int i1 = 0;
    #pragma unroll
    for (int e = 1; e < 16; ++e) { if (s[e] > b1) { b1 = s[e]; i1 = e; } }
    float b2 = -INFINITY; int i2 = 0;
    #pragma unroll
    for (int e = 0; e < 16; ++e) { if (e != i1 && s[e] > b2) { b2 = s[e]; i2 = e; } }

    float t2 = expf(b2 - b1);
    float p1 = 1.f / (1.f + t2);
    float p2 = t2 / (1.f + t2);

    float v[16];
    #pragma unroll
    for (int e = 0; e < 16; ++e)
      v[e] = (e == i1) ? p1 : ((e == i2) ? p2 : 0.f);

    float* orow = out + (size_t)row_g * NEXP;
    *(float4*)(orow + 0)  = make_float4(v[0], v[1], v[2], v[3]);
    *(float4*)(orow + 4)  = make_float4(v[4], v[5], v[6], v[7]);
    *(float4*)(orow + 8)  = make_float4(v[8], v[9], v[10], v[11]);
    *(float4*)(orow + 12) = make_float4(v[12], v[13], v[14], v[15]);

    float* oidx = out + IDX_OFF + (size_t)row_g * 2;
    *(float2*)oidx = make_float2((float)i1, (float)i2);

    // per-block expert-prob sums over 16 rows (butterfly within lanes 0..15)
    #pragma unroll
    for (int m = 1; m < 16; m <<= 1) {
      #pragma unroll
      for (int e = 0; e < 16; ++e) v[e] += __shfl_xor(v[e], m, 16);
    }
    if (tid == 0) {
      float* wp = wsp + (size_t)blockIdx.x * 16;
      *(float4*)(wp + 0)  = make_float4(v[0], v[1], v[2], v[3]);
      *(float4*)(wp + 4)  = make_float4(v[4], v[5], v[6], v[7]);
      *(float4*)(wp + 8)  = make_float4(v[8], v[9], v[10], v[11]);
      *(float4*)(wp + 12) = make_float4(v[12], v[13], v[14], v[15]);
    }
  }
}

__global__ void router_aux_k(const float* __restrict__ wsp, float* __restrict__ out_aux) {
  __shared__ float red[16][17];
  __shared__ float sq[16];
  const int t = threadIdx.x;
  const int e = t & 15;
  const int g = t >> 4;
  float ssum = 0.f;
  for (int b = 0; b < 64; ++b) ssum += wsp[(size_t)(g * 64 + b) * 16 + e];
  red[g][e] = ssum;
  __syncthreads();
  if (t < 16) {
    float tot = 0.f;
    #pragma unroll
    for (int gg = 0; gg < 16; ++gg) tot += red[gg][t];
    float diff = tot * (1.f / 16384.f) - 0.0625f;
    sq[t] = diff * diff;
  }
  __syncthreads();
  if (t == 0) {
    float a = 0.f;
    #pragma unroll
    for (int i = 0; i < 16; ++i) a += sq[i];
    *out_aux = a;
  }
}

extern "C" void kernel_launch(void* const* d_in, const int* in_sizes, int n_in,
                              void* d_out, int out_size, void* d_ws, size_t ws_size,
                              hipStream_t stream) {
  const float* x   = (const float*)d_in[0];
  const float* wr  = (const float*)d_in[1];
  const float* br  = (const float*)d_in[2];
  const float* wn  = (const float*)d_in[3];
  const float* bn  = (const float*)d_in[4];
  const float* eps = (const float*)d_in[5];
  float* out = (float*)d_out;
  float* wsp = (float*)d_ws;  // 1024 blocks * 16 floats = 64 KB partials

  router_main_k<<<NBLK, 256, 0, stream>>>(x, wr, br, wn, bn, eps, out, wsp);
  router_aux_k<<<1, 256, 0, stream>>>(wsp, out + AUX_OFF);
}

// Round 3
// 73.773 us; speedup vs baseline: 7.8043x; 7.8043x over previous
//
#include <hip/hip_runtime.h>
#include <math.h>

// NoisyTopkRouter: B=4 S=4096 D=2048 E=16 K=2, TEMPERATURE=1. rows = 16384.
// out layout (fp32): router_output [16384*16] | indices-as-float [16384*2] | aux_loss [1]
// Round 3: 512 blocks x 32 rows, 4 waves x 512-d slice. x staged via per-wave
// double-buffered LDS (register prefetch, no barriers in main loop); W read
// directly from global (L2-hot, 8-way wave broadcast). No launch_bounds cap
// beyond block size (round-2 spill lesson: VGPR cap 128 < demand -> 1.5GB scratch).

#define DDIM 2048
#define NEXP 16
#define RPB 32             // rows per block
#define WAVE_D 512
#define CHUNK 32
#define NCH 16             // WAVE_D / CHUNK
#define XSTR 36            // x LDS row stride (32 + 4 pad -> bank rotation by 4/row)
#define WREG 2304          // floats per wave region: x dbuf 2*32*36
#define IDX_OFF 262144
#define AUX_OFF 294912
#define NBLK 512

__global__ __launch_bounds__(256) void router_main_k(
    const float* __restrict__ x, const float* __restrict__ wr,
    const float* __restrict__ br, const float* __restrict__ wn,
    const float* __restrict__ bn, const float* __restrict__ eps,
    float* __restrict__ out, float* __restrict__ wsp) {
  __shared__ float smem[4 * WREG];  // 36864 B

  const int tid  = threadIdx.x;
  const int wave = tid >> 6;
  const int lane = tid & 63;
  const int rg   = lane >> 3;        // 0..7 -> rows {rg, rg+8, rg+16, rg+24}
  const int q4   = (lane & 7) * 4;   // 0..28: cols 0..15 = route, 16..31 = noise
  const int row_base = blockIdx.x * RPB;

  float* xreg = smem + wave * WREG;  // [2][32][XSTR]

  // staging: lane covers rows {rg + 8t}, 16B column dc; 8 lanes = 128B/row
  const int dc = q4;                 // (lane&7)*4
  const float* xb = x + (size_t)(row_base + rg) * DDIM + wave * WAVE_D + dc;
  const int xs_off = rg * XSTR + dc;

  // per-lane W pointer: route cols for q<4, noise cols for q>=4 (same slice)
  const int wq = q4 & 15;
  const float* wbase = (q4 < 16 ? wr : wn) + (size_t)(wave * WAVE_D) * NEXP + wq;

  float4 acc[4];
  #pragma unroll
  for (int i = 0; i < 4; ++i) acc[i] = make_float4(0.f, 0.f, 0.f, 0.f);

  // ---- prologue: stage chunk 0 into buffer 0 ----
  float4 xp[4];
  #pragma unroll
  for (int t = 0; t < 4; ++t) xp[t] = *(const float4*)(xb + (size_t)t * 8 * DDIM);
  #pragma unroll
  for (int t = 0; t < 4; ++t) *(float4*)(xreg + xs_off + t * 8 * XSTR) = xp[t];

  for (int k = 0; k < NCH; ++k) {
    const int cur = k & 1;
    // prefetch chunk k+1 (x) into registers — in flight during compute
    if (k + 1 < NCH) {
      #pragma unroll
      for (int t = 0; t < 4; ++t)
        xp[t] = *(const float4*)(xb + (size_t)t * 8 * DDIM + (k + 1) * CHUNK);
    }
    const float* xbuf = xreg + cur * 1152;
    const float* wch  = wbase + (size_t)(k * CHUNK) * NEXP;
    #pragma unroll
    for (int dd = 0; dd < CHUNK; dd += 4) {
      float4 w0 = *(const float4*)(wch + (dd + 0) * NEXP);
      float4 w1 = *(const float4*)(wch + (dd + 1) * NEXP);
      float4 w2 = *(const float4*)(wch + (dd + 2) * NEXP);
      float4 w3 = *(const float4*)(wch + (dd + 3) * NEXP);
      #pragma unroll
      for (int i = 0; i < 4; ++i) {
        float4 xv = *(const float4*)(xbuf + (rg + 8 * i) * XSTR + dd);
        acc[i].x = fmaf(xv.w, w3.x, fmaf(xv.z, w2.x, fmaf(xv.y, w1.x, fmaf(xv.x, w0.x, acc[i].x))));
        acc[i].y = fmaf(xv.w, w3.y, fmaf(xv.z, w2.y, fmaf(xv.y, w1.y, fmaf(xv.x, w0.y, acc[i].y))));
        acc[i].z = fmaf(xv.w, w3.z, fmaf(xv.z, w2.z, fmaf(xv.y, w1.z, fmaf(xv.x, w0.z, acc[i].z))));
        acc[i].w = fmaf(xv.w, w3.w, fmaf(xv.z, w2.w, fmaf(xv.y, w1.w, fmaf(xv.x, w0.w, acc[i].w))));
      }
    }
    if (k + 1 < NCH) {
      float* xnxt = xreg + (cur ^ 1) * 1152;
      #pragma unroll
      for (int t = 0; t < 4; ++t) *(float4*)(xnxt + xs_off + t * 8 * XSTR) = xp[t];
    }
  }

  // ---- cross-wave reduction + per-row epilogue ----
  __syncthreads();                      // all waves done with their staging buffers
  float* pb = smem + wave * 1152;       // partials [32][XSTR] per wave (reuse LDS)
  #pragma unroll
  for (int i = 0; i < 4; ++i)
    *(float4*)(pb + (rg + 8 * i) * XSTR + q4) = acc[i];
  __syncthreads();

  if (tid < RPB) {
    const int row_l = tid;
    const int row_g = row_base + row_l;
    float c[32];
    #pragma unroll
    for (int g = 0; g < 8; ++g) {
      float4 a0 = *(const float4*)(smem + 0 * 1152 + row_l * XSTR + g * 4);
      float4 a1 = *(const float4*)(smem + 1 * 1152 + row_l * XSTR + g * 4);
      float4 a2 = *(const float4*)(smem + 2 * 1152 + row_l * XSTR + g * 4);
      float4 a3 = *(const float4*)(smem + 3 * 1152 + row_l * XSTR + g * 4);
      c[g * 4 + 0] = (a0.x + a1.x) + (a2.x + a3.x);
      c[g * 4 + 1] = (a0.y + a1.y) + (a2.y + a3.y);
      c[g * 4 + 2] = (a0.z + a1.z) + (a2.z + a3.z);
      c[g * 4 + 3] = (a0.w + a1.w) + (a2.w + a3.w);
    }

    float brv[16], bnv[16], ev[16];
    #pragma unroll
    for (int g = 0; g < 4; ++g) {
      *(float4*)(brv + g * 4) = *(const float4*)(br + g * 4);
      *(float4*)(bnv + g * 4) = *(const float4*)(bn + g * 4);
      *(float4*)(ev  + g * 4) = *(const float4*)(eps + (size_t)row_g * NEXP + g * 4);
    }

    float s[16];
    #pragma unroll
    for (int e = 0; e < 16; ++e) {
      float lg = c[e] + brv[e];
      float nz = c[16 + e] + bnv[e];
      float sp = fmaxf(nz, 0.f) + log1pf(expf(-fabsf(nz)));  // stable softplus
      s[e] = lg + ev[e] * sp;                                 // TEMPERATURE == 1
    }

    // top-2 (ties -> lowest index, matching lax.top_k)
    float b1 = s[0]; int i1 = 0;
    #pragma unroll
    for (int e = 1; e < 16; ++e) { if (s[e] > b1) { b1 = s[e]; i1 = e; } }
    float b2 = -INFINITY; int i2 = 0;
    #pragma unroll
    for (int e = 0; e < 16; ++e) { if (e != i1 && s[e] > b2) { b2 = s[e]; i2 = e; } }

    float t2 = expf(b2 - b1);
    float p1 = 1.f / (1.f + t2);
    float p2 = t2 / (1.f + t2);

    float v[16];
    #pragma unroll
    for (int e = 0; e < 16; ++e)
      v[e] = (e == i1) ? p1 : ((e == i2) ? p2 : 0.f);

    float* orow = out + (size_t)row_g * NEXP;
    *(float4*)(orow + 0)  = make_float4(v[0], v[1], v[2], v[3]);
    *(float4*)(orow + 4)  = make_float4(v[4], v[5], v[6], v[7]);
    *(float4*)(orow + 8)  = make_float4(v[8], v[9], v[10], v[11]);
    *(float4*)(orow + 12) = make_float4(v[12], v[13], v[14], v[15]);

    float* oidx = out + IDX_OFF + (size_t)row_g * 2;
    *(float2*)oidx = make_float2((float)i1, (float)i2);

    // per-block expert-prob sums over 32 rows (butterfly, lanes 0..31 of wave 0)
    #pragma unroll
    for (int m = 1; m < 32; m <<= 1) {
      #pragma unroll
      for (int e = 0; e < 16; ++e) v[e] += __shfl_xor(v[e], m, 32);
    }
    if (tid == 0) {
      float* wp = wsp + (size_t)blockIdx.x * 16;
      *(float4*)(wp + 0)  = make_float4(v[0], v[1], v[2], v[3]);
      *(float4*)(wp + 4)  = make_float4(v[4], v[5], v[6], v[7]);
      *(float4*)(wp + 8)  = make_float4(v[8], v[9], v[10], v[11]);
      *(float4*)(wp + 12) = make_float4(v[12], v[13], v[14], v[15]);
    }
  }
}

__global__ void router_aux_k(const float* __restrict__ wsp, float* __restrict__ out_aux) {
  __shared__ float red[16][17];
  __shared__ float sq[16];
  const int t = threadIdx.x;
  const int e = t & 15;
  const int g = t >> 4;
  float ssum = 0.f;
  for (int b = 0; b < 32; ++b) ssum += wsp[(size_t)(g * 32 + b) * 16 + e];
  red[g][e] = ssum;
  __syncthreads();
  if (t < 16) {
    float tot = 0.f;
    #pragma unroll
    for (int gg = 0; gg < 16; ++gg) tot += red[gg][t];
    float diff = tot * (1.f / 16384.f) - 0.0625f;
    sq[t] = diff * diff;
  }
  __syncthreads();
  if (t == 0) {
    float a = 0.f;
    #pragma unroll
    for (int i = 0; i < 16; ++i) a += sq[i];
    *out_aux = a;
  }
}

extern "C" void kernel_launch(void* const* d_in, const int* in_sizes, int n_in,
                              void* d_out, int out_size, void* d_ws, size_t ws_size,
                              hipStream_t stream) {
  const float* x   = (const float*)d_in[0];
  const float* wr  = (const float*)d_in[1];
  const float* br  = (const float*)d_in[2];
  const float* wn  = (const float*)d_in[3];
  const float* bn  = (const float*)d_in[4];
  const float* eps = (const float*)d_in[5];
  float* out = (float*)d_out;
  float* wsp = (float*)d_ws;  // 512 blocks * 16 floats = 32 KB partials

  router_main_k<<<NBLK, 256, 0, stream>>>(x, wr, br, wn, bn, eps, out, wsp);
  router_aux_k<<<1, 256, 0, stream>>>(wsp, out + AUX_OFF);
}

// Round 5
// 64.452 us; speedup vs baseline: 8.9329x; 1.1446x over previous
//
#include <hip/hip_runtime.h>
#include <math.h>

// NoisyTopkRouter: B=4 S=4096 D=2048 E=16 K=2, TEMPERATURE=1. rows = 16384.
// out layout (fp32): router_output [16384*16] | indices-as-float [16384*2] | aux_loss [1]
// Round 5: 512 blocks x 32 rows, 8 waves x 256-d slice.
//  - W software-pipelined one 4-d group ahead into ping-pong registers wp[2][4]
//    (kills the L2-latency-on-critical-path stall of rounds 3/4).
//  - x via per-wave dbuf LDS [2][32][16] with dgroup XOR-swizzle g^(row&3)
//    (read-side <=2-way conflicts = free; static LDS 37.4KB << 64KB limit).
//  - launch_bounds(512,4): cap 128 VGPR >= ~100 demand -> 16 waves/CU.
//  - partial/reduce LDS strides written as a matched pair (round-4 bug fix).

#define DDIM 2048
#define NEXP 16
#define RPB 32             // rows per block
#define WAVE_D 256         // d-slice per wave (8 waves cover 2048)
#define NCH 16             // chunks of 16 d per wave
#define NGRP 64            // 4-d groups per wave (WAVE_D/4)
#define RED_OFF 8192       // reduced partials [32][36] after 8*1024 x/partial regions
#define IDX_OFF 262144
#define AUX_OFF 294912
#define NBLK 512

__global__ __launch_bounds__(512, 4) void router_main_k(
    const float* __restrict__ x, const float* __restrict__ wr,
    const float* __restrict__ br, const float* __restrict__ wn,
    const float* __restrict__ bn, const float* __restrict__ eps,
    float* __restrict__ out, float* __restrict__ wsp) {
  __shared__ float smem[8 * 1024 + 32 * 36];  // 37376 B

  const int tid  = threadIdx.x;
  const int wave = tid >> 6;
  const int lane = tid & 63;
  const int rg   = lane >> 3;        // 0..7 -> rows {rg, rg+8, rg+16, rg+24}
  const int q    = lane & 7;         // col group: q<4 route cols 4q..; q>=4 noise
  const int q4   = q * 4;
  const int row_base = blockIdx.x * RPB;

  float* xregion = smem + wave * 1024;   // [2][32][16] dbuf, swizzled

  // ---- staging map: lane covers row sr, dgroups {sc0, sc0+1} of each 16-d chunk
  const int sr  = lane & 31;
  const int sc0 = (lane >> 5) * 2;
  const float* xg = x + (size_t)(row_base + sr) * DDIM + wave * WAVE_D + sc0 * 4;
  const int ls0 = sr * 16 + (((sc0    ) ^ (sr & 3)) << 2);
  const int ls1 = sr * 16 + (((sc0 ^ 1) ^ (sr & 3)) << 2);

  // ---- per-lane W pointer (route for q<4, noise for q>=4), 16B per 4-d row
  const float* wbase = (q < 4 ? wr : wn) + (size_t)(wave * WAVE_D) * NEXP + (q4 & 15);

  float4 acc[4];
  #pragma unroll
  for (int i = 0; i < 4; ++i) acc[i] = make_float4(0.f, 0.f, 0.f, 0.f);

  float4 wp[2][4];   // ping-pong W pipeline (fully unrolled -> registers)
  float4 xp0, xp1;

  // ---- prologue: W group 0 + x chunk 0 ----
  #pragma unroll
  for (int j = 0; j < 4; ++j) wp[0][j] = *(const float4*)(wbase + j * NEXP);
  xp0 = *(const float4*)(xg);
  xp1 = *(const float4*)(xg + 4);
  *(float4*)(xregion + ls0) = xp0;
  *(float4*)(xregion + ls1) = xp1;

  const int swr = rg & 3;

  for (int k = 0; k < NCH; ++k) {
    const float* xb = xregion + (k & 1) * 512;
    #pragma unroll
    for (int gg = 0; gg < 4; ++gg) {
      const int G = (k << 2) + gg;
      const int P = gg & 1;
      // prefetch W for group G+1 into the other bank
      if (G + 1 < NGRP) {
        const float* wl = wbase + (size_t)(G + 1) * 4 * NEXP;
        #pragma unroll
        for (int j = 0; j < 4; ++j) wp[P ^ 1][j] = *(const float4*)(wl + j * NEXP);
      }
      // prefetch x chunk k+1 (issued early, consumed at gg==3)
      if (gg == 0 && k + 1 < NCH) {
        xp0 = *(const float4*)(xg + (k + 1) * 16);
        xp1 = *(const float4*)(xg + (k + 1) * 16 + 4);
      }
      // compute: 4 rows x 4 cols x 4 d
      #pragma unroll
      for (int i = 0; i < 4; ++i) {
        const float4 xv = *(const float4*)(xb + ((rg + 8 * i) << 4) + ((gg ^ swr) << 2));
        acc[i].x = fmaf(xv.w, wp[P][3].x, fmaf(xv.z, wp[P][2].x, fmaf(xv.y, wp[P][1].x, fmaf(xv.x, wp[P][0].x, acc[i].x))));
        acc[i].y = fmaf(xv.w, wp[P][3].y, fmaf(xv.z, wp[P][2].y, fmaf(xv.y, wp[P][1].y, fmaf(xv.x, wp[P][0].y, acc[i].y))));
        acc[i].z = fmaf(xv.w, wp[P][3].z, fmaf(xv.z, wp[P][2].z, fmaf(xv.y, wp[P][1].z, fmaf(xv.x, wp[P][0].z, acc[i].z))));
        acc[i].w = fmaf(xv.w, wp[P][3].w, fmaf(xv.z, wp[P][2].w, fmaf(xv.y, wp[P][1].w, fmaf(xv.x, wp[P][0].w, acc[i].w))));
      }
      // write prefetched x into the other buffer
      if (gg == 3 && k + 1 < NCH) {
        float* xw = xregion + ((k + 1) & 1) * 512;
        *(float4*)(xw + ls0) = xp0;
        *(float4*)(xw + ls1) = xp1;
      }
    }
  }

  // ---- partials into own region [32][32], swizzled (q ^ row&7) ----
  {
    float* pr = xregion;
    const int psw = (q ^ rg) << 2;
    #pragma unroll
    for (int i = 0; i < 4; ++i)
      *(float4*)(pr + ((rg + 8 * i) << 5) + psw) = acc[i];
  }
  __syncthreads();

  // ---- stage 1: cross-wave reduce (8 -> 1), matching swizzle ----
  if (tid < 256) {
    const int row = tid >> 3;
    const int g   = tid & 7;
    const int rsw = (g ^ (row & 7)) << 2;
    float4 s = make_float4(0.f, 0.f, 0.f, 0.f);
    #pragma unroll
    for (int w = 0; w < 8; ++w) {
      float4 a = *(const float4*)(smem + (w << 10) + (row << 5) + rsw);
      s.x += a.x; s.y += a.y; s.z += a.z; s.w += a.w;
    }
    *(float4*)(smem + RED_OFF + row * 36 + g * 4) = s;
  }
  __syncthreads();

  // ---- stage 2: per-row epilogue (32 rows, lanes 0..31 of wave 0) ----
  if (tid < RPB) {
    const int row_l = tid;
    const int row_g = row_base + row_l;
    float c[32];
    #pragma unroll
    for (int g = 0; g < 8; ++g) {
      float4 a = *(const float4*)(smem + RED_OFF + row_l * 36 + g * 4);
      c[g * 4 + 0] = a.x; c[g * 4 + 1] = a.y; c[g * 4 + 2] = a.z; c[g * 4 + 3] = a.w;
    }

    float brv[16], bnv[16], ev[16];
    #pragma unroll
    for (int g = 0; g < 4; ++g) {
      *(float4*)(brv + g * 4) = *(const float4*)(br + g * 4);
      *(float4*)(bnv + g * 4) = *(const float4*)(bn + g * 4);
      *(float4*)(ev  + g * 4) = *(const float4*)(eps + (size_t)row_g * NEXP + g * 4);
    }

    float s[16];
    #pragma unroll
    for (int e = 0; e < 16; ++e) {
      float lg = c[e] + brv[e];
      float nz = c[16 + e] + bnv[e];
      float sp = fmaxf(nz, 0.f) + log1pf(expf(-fabsf(nz)));  // stable softplus
      s[e] = lg + ev[e] * sp;                                 // TEMPERATURE == 1
    }

    // top-2 (ties -> lowest index, matching lax.top_k)
    float b1 = s[0]; int i1 = 0;
    #pragma unroll
    for (int e = 1; e < 16; ++e) { if (s[e] > b1) { b1 = s[e]; i1 = e; } }
    float b2 = -INFINITY; int i2 = 0;
    #pragma unroll
    for (int e = 0; e < 16; ++e) { if (e != i1 && s[e] > b2) { b2 = s[e]; i2 = e; } }

    float t2 = expf(b2 - b1);
    float p1 = 1.f / (1.f + t2);
    float p2 = t2 / (1.f + t2);

    float v[16];
    #pragma unroll
    for (int e = 0; e < 16; ++e)
      v[e] = (e == i1) ? p1 : ((e == i2) ? p2 : 0.f);

    float* orow = out + (size_t)row_g * NEXP;
    *(float4*)(orow + 0)  = make_float4(v[0], v[1], v[2], v[3]);
    *(float4*)(orow + 4)  = make_float4(v[4], v[5], v[6], v[7]);
    *(float4*)(orow + 8)  = make_float4(v[8], v[9], v[10], v[11]);
    *(float4*)(orow + 12) = make_float4(v[12], v[13], v[14], v[15]);

    float* oidx = out + IDX_OFF + (size_t)row_g * 2;
    *(float2*)oidx = make_float2((float)i1, (float)i2);

    // per-block expert-prob sums over 32 rows (butterfly, lanes 0..31)
    #pragma unroll
    for (int m = 1; m < 32; m <<= 1) {
      #pragma unroll
      for (int e = 0; e < 16; ++e) v[e] += __shfl_xor(v[e], m, 32);
    }
    if (tid == 0) {
      float* wp2 = wsp + (size_t)blockIdx.x * 16;
      *(float4*)(wp2 + 0)  = make_float4(v[0], v[1], v[2], v[3]);
      *(float4*)(wp2 + 4)  = make_float4(v[4], v[5], v[6], v[7]);
      *(float4*)(wp2 + 8)  = make_float4(v[8], v[9], v[10], v[11]);
      *(float4*)(wp2 + 12) = make_float4(v[12], v[13], v[14], v[15]);
    }
  }
}

__global__ void router_aux_k(const float* __restrict__ wsp, float* __restrict__ out_aux) {
  __shared__ float red[16][17];
  __shared__ float sq[16];
  const int t = threadIdx.x;
  const int e = t & 15;
  const int g = t >> 4;
  float ssum = 0.f;
  for (int b = 0; b < 32; ++b) ssum += wsp[(size_t)(g * 32 + b) * 16 + e];
  red[g][e] = ssum;
  __syncthreads();
  if (t < 16) {
    float tot = 0.f;
    #pragma unroll
    for (int gg = 0; gg < 16; ++gg) tot += red[gg][t];
    float diff = tot * (1.f / 16384.f) - 0.0625f;
    sq[t] = diff * diff;
  }
  __syncthreads();
  if (t == 0) {
    float a = 0.f;
    #pragma unroll
    for (int i = 0; i < 16; ++i) a += sq[i];
    *out_aux = a;
  }
}

extern "C" void kernel_launch(void* const* d_in, const int* in_sizes, int n_in,
                              void* d_out, int out_size, void* d_ws, size_t ws_size,
                              hipStream_t stream) {
  const float* x   = (const float*)d_in[0];
  const float* wr  = (const float*)d_in[1];
  const float* br  = (const float*)d_in[2];
  const float* wn  = (const float*)d_in[3];
  const float* bn  = (const float*)d_in[4];
  const float* eps = (const float*)d_in[5];
  float* out = (float*)d_out;
  float* wsp = (float*)d_ws;  // 512 blocks * 16 floats = 32 KB partials

  router_main_k<<<NBLK, 512, 0, stream>>>(x, wr, br, wn, bn, eps, out, wsp);
  router_aux_k<<<1, 256, 0, stream>>>(wsp, out + AUX_OFF);
}